// Round 7
// baseline (228.557 us; speedup 1.0000x reference)
//
#include <hip/hip_runtime.h>

#define NB 1024
#define LQ 20
#define LD 200
#define E4 32
#define NK 21
#define NPAIRS 4
#define GRID 512

typedef __attribute__((ext_vector_type(8))) short bf16x8;
typedef __attribute__((ext_vector_type(4))) float f32x4;

__device__ __forceinline__ unsigned short bfr(float f) {
    unsigned u = __builtin_bit_cast(unsigned, f);
    return (unsigned short)((u + 0x7FFFu + ((u >> 16) & 1u)) >> 16);   // RNE
}

__device__ __forceinline__ float sq8(uint4 u) {   // sum of squares of 8 bf16
    float s = 0.f;
    unsigned w;
    #define SQ2(W) { \
        float lo = __builtin_bit_cast(float, (W) << 16); \
        float hi = __builtin_bit_cast(float, (W) & 0xFFFF0000u); \
        s = fmaf(lo, lo, s); s = fmaf(hi, hi, s); }
    w = u.x; SQ2(w) w = u.y; SQ2(w) w = u.z; SQ2(w) w = u.w; SQ2(w)
    #undef SQ2
    return s;
}

__device__ __forceinline__ float fast_exp2(float x) {
#if __has_builtin(__builtin_amdgcn_exp2f)
    return __builtin_amdgcn_exp2f(x);
#else
    return __expf(x * 0.69314718056f);
#endif
}

// ============ Kernel 0: cast emb fp32 -> bf16 table in workspace ============
__global__ __launch_bounds__(256) void knrm_cast(
    const float* __restrict__ emb, unsigned short* __restrict__ ebf, int n4)
{
    const float4* src = (const float4*)emb;
    ushort4* dst = (ushort4*)ebf;
    for (int p = blockIdx.x * 256 + threadIdx.x; p < n4; p += gridDim.x * 256) {
        float4 v = src[p];
        ushort4 o;
        o.x = bfr(v.x); o.y = bfr(v.y); o.z = bfr(v.z); o.w = bfr(v.w);
        dst[p] = o;
    }
}

// ============ Kernel 1: persistent pipelined KNRM ===========================
// Grid 512, 4 pairs/block. Pair u+1's gathers issued before pair u's Phase C.
__global__ __launch_bounds__(256, 2) void knrm_pipe(
    const int* __restrict__ q1, const int* __restrict__ d1,
    const int* __restrict__ q2, const int* __restrict__ d2,
    const unsigned short* __restrict__ ebf,
    const float* __restrict__ W1, const float* __restrict__ b1,
    const float* __restrict__ W2, const float* __restrict__ b2,
    const float* __restrict__ W3, const float* __restrict__ b3,
    float* __restrict__ logits)
{
    __shared__ float sM[2][LD][20];     // 31.25 KB double-buffered
    __shared__ float sPhi[2][LQ][NK];   // 3.3 KB double-buffered

    const int bid  = blockIdx.x;
    const int t    = threadIdx.x;
    const int lane = t & 63, wave = t >> 6;
    const int c    = lane & 15, quad = lane >> 4;
    const uint4* et = (const uint4*)ebf;

    for (int p = t; p < LQ * NK; p += 256) ((float*)sPhi[0])[p] = 0.f;

    uint4 cA[8];        // A fragments: [Mt*4 + ks]
    uint4 cB[4][4];     // B fragments: [tile-slot][ks]

    auto prefetch = [&](int np) {
        const int nb  = np & (NB - 1);
        const int npd = np >> 10;
        const int* __restrict__ nqi = npd ? q2 : q1;
        const int* __restrict__ ndi = npd ? d2 : d1;
        const int qid0 = nqi[nb * LQ + c];                                  // rows 0..15
        const int qid1 = nqi[nb * LQ + (16 + c < LQ ? 16 + c : LQ - 1)];    // rows 16..19 (clamped)
        const uint4* qr0 = et + (size_t)qid0 * 16;
        const uint4* qr1 = et + (size_t)qid1 * 16;
        #pragma unroll
        for (int ks = 0; ks < 4; ++ks) cA[ks]     = qr0[ks * 4 + quad];
        #pragma unroll
        for (int ks = 0; ks < 4; ++ks) cA[4 + ks] = qr1[ks * 4 + quad];
        #pragma unroll
        for (int u2 = 0; u2 < 4; ++u2) {
            const int tile = wave * 4 + u2;
            if (tile * 16 < LD) {
                const int j  = tile * 16 + c;
                const int id = ndi[nb * LD + (j < LD ? j : LD - 1)];
                const uint4* dr = et + (size_t)id * 16;
                #pragma unroll
                for (int ks = 0; ks < 4; ++ks) cB[u2][ks] = dr[ks * 4 + quad];
            }
        }
    };

    prefetch(bid);   // pair 0

    for (int u = 0; u < NPAIRS; ++u) {
        const int ub = u & 1;

        // ---- Phase A/B: norms + MFMA + store M to sM[ub] ----
        float qs0 = sq8(cA[0]) + sq8(cA[1]) + sq8(cA[2]) + sq8(cA[3]);
        qs0 += __shfl_xor(qs0, 16); qs0 += __shfl_xor(qs0, 32);
        const float rq0 = rsqrtf(qs0 + 1e-6f);
        float qs1 = sq8(cA[4]) + sq8(cA[5]) + sq8(cA[6]) + sq8(cA[7]);
        qs1 += __shfl_xor(qs1, 16); qs1 += __shfl_xor(qs1, 32);
        const float rq1 = rsqrtf(qs1 + 1e-6f);
        float rqv0[4], rqv1[4];
        #pragma unroll
        for (int r = 0; r < 4; ++r) {
            rqv0[r] = __shfl(rq0, quad * 4 + r);
            rqv1[r] = __shfl(rq1, quad * 4 + r);
        }

        #pragma unroll
        for (int u2 = 0; u2 < 4; ++u2) {
            const int tile = wave * 4 + u2;
            if (tile * 16 < LD) {
                float dsq = sq8(cB[u2][0]) + sq8(cB[u2][1]) + sq8(cB[u2][2]) + sq8(cB[u2][3]);
                dsq += __shfl_xor(dsq, 16); dsq += __shfl_xor(dsq, 32);
                const float rd = rsqrtf(dsq + 1e-6f);

                f32x4 acc0 = {0.f, 0.f, 0.f, 0.f};
                f32x4 acc1 = {0.f, 0.f, 0.f, 0.f};
                #pragma unroll
                for (int ks = 0; ks < 4; ++ks) {
                    bf16x8 bfrag = __builtin_bit_cast(bf16x8, cB[u2][ks]);
                    acc0 = __builtin_amdgcn_mfma_f32_16x16x32_bf16(
                               __builtin_bit_cast(bf16x8, cA[ks]),     bfrag, acc0, 0, 0, 0);
                    acc1 = __builtin_amdgcn_mfma_f32_16x16x32_bf16(
                               __builtin_bit_cast(bf16x8, cA[4 + ks]), bfrag, acc1, 0, 0, 0);
                }
                const int j = tile * 16 + c;
                if (j < LD) {
                    // C layout: col = lane&15 (=j), row = quad*4 + reg
                    float4 v0;
                    v0.x = acc0[0] * rqv0[0] * rd;
                    v0.y = acc0[1] * rqv0[1] * rd;
                    v0.z = acc0[2] * rqv0[2] * rd;
                    v0.w = acc0[3] * rqv0[3] * rd;
                    *(float4*)&sM[ub][j][quad * 4] = v0;
                    if (quad == 0) {
                        float4 v1;
                        v1.x = acc1[0] * rqv1[0] * rd;
                        v1.y = acc1[1] * rqv1[1] * rd;
                        v1.z = acc1[2] * rqv1[2] * rd;
                        v1.w = acc1[3] * rqv1[3] * rd;
                        *(float4*)&sM[ub][j][16] = v1;
                    }
                }
            }
        }
        __syncthreads();

        // ---- issue next pair's gathers NOW; they ride out latency under Phase C ----
        if (u + 1 < NPAIRS) prefetch(bid + GRID * (u + 1));

        // ---- Phase C: RBF kernels on sM[ub] -> sPhi[ub] ----
        if (t < 240) {
            const int i = t / 12, slice = t % 12;
            const int j0 = slice * 17;
            const int j1 = (j0 + 17 < LD) ? (j0 + 17) : LD;
            const float C2  = -72.13475204f;     // -50*log2(e)
            const float B2  = 144.26950408f;     // 100*log2(e)
            const float C2E = -721347.5204f;     // -5e5*log2(e)

            float s00 = 0.f, s01 = 0.f, s02 = 0.f, s03 = 0.f, s04 = 0.f;
            float s05 = 0.f, s06 = 0.f, s07 = 0.f, s08 = 0.f, s09 = 0.f;
            float s10 = 0.f, s11 = 0.f, s12 = 0.f, s13 = 0.f, s14 = 0.f;
            float s15 = 0.f, s16 = 0.f, s17 = 0.f, s18 = 0.f, s19 = 0.f;
            float s20 = 0.f;

            for (int j = j0; j < j1; ++j) {
                const float m  = sM[ub][j][i];
                const float a2 = C2 * (m * m);
                const float bb = B2 * m;
                #define KS(ACC, MU) \
                    ACC += fast_exp2(fmaf((MU), bb, a2 + (-72.13475204f) * ((MU) * (MU))));
                KS(s00, -0.95f) KS(s01, -0.85f) KS(s02, -0.75f) KS(s03, -0.65f)
                KS(s04, -0.55f) KS(s05, -0.45f) KS(s06, -0.35f) KS(s07, -0.25f)
                KS(s08, -0.15f) KS(s09, -0.05f) KS(s10,  0.05f) KS(s11,  0.15f)
                KS(s12,  0.25f) KS(s13,  0.35f) KS(s14,  0.45f) KS(s15,  0.55f)
                KS(s16,  0.65f) KS(s17,  0.75f) KS(s18,  0.85f) KS(s19,  0.95f)
                #undef KS
                const float dd = m - 1.0f;
                s20 += fast_exp2(dd * dd * C2E);
            }
            atomicAdd(&sPhi[ub][i][ 0], s00); atomicAdd(&sPhi[ub][i][ 1], s01);
            atomicAdd(&sPhi[ub][i][ 2], s02); atomicAdd(&sPhi[ub][i][ 3], s03);
            atomicAdd(&sPhi[ub][i][ 4], s04); atomicAdd(&sPhi[ub][i][ 5], s05);
            atomicAdd(&sPhi[ub][i][ 6], s06); atomicAdd(&sPhi[ub][i][ 7], s07);
            atomicAdd(&sPhi[ub][i][ 8], s08); atomicAdd(&sPhi[ub][i][ 9], s09);
            atomicAdd(&sPhi[ub][i][10], s10); atomicAdd(&sPhi[ub][i][11], s11);
            atomicAdd(&sPhi[ub][i][12], s12); atomicAdd(&sPhi[ub][i][13], s13);
            atomicAdd(&sPhi[ub][i][14], s14); atomicAdd(&sPhi[ub][i][15], s15);
            atomicAdd(&sPhi[ub][i][16], s16); atomicAdd(&sPhi[ub][i][17], s17);
            atomicAdd(&sPhi[ub][i][18], s18); atomicAdd(&sPhi[ub][i][19], s19);
            atomicAdd(&sPhi[ub][i][20], s20);
        }
        __syncthreads();

        // ---- wave 0: log1p + MLP via shuffles (no barriers); others: zero next phi ----
        if (wave == 0) {
            float sx = 0.f;
            if (lane < NK) {
                #pragma unroll
                for (int i = 0; i < LQ; ++i) sx += __logf(1.0f + sPhi[ub][i][lane]);
            }
            float v1 = (lane < 10) ? b1[lane] : 0.f;
            #pragma unroll
            for (int k = 0; k < NK; ++k) {
                const float xk = __shfl(sx, k);
                if (lane < 10) v1 = fmaf(W1[lane * NK + k], xk, v1);
            }
            const float h1 = fmaxf(v1, 0.f);
            float v2 = (lane < 5) ? b2[lane] : 0.f;
            #pragma unroll
            for (int k = 0; k < 10; ++k) {
                const float hk = __shfl(h1, k);
                if (lane < 5) v2 = fmaf(W2[lane * 10 + k], hk, v2);
            }
            const float h2 = fmaxf(v2, 0.f);
            float v3 = b3[0];
            #pragma unroll
            for (int k = 0; k < 5; ++k) {
                const float hk = __shfl(h2, k);
                v3 = fmaf(W3[k], hk, v3);
            }
            if (lane == 0) {
                const int pair = bid + GRID * u;
                logits[(pair >> 10) * NB + (pair & (NB - 1))] = v3;
            }
        } else {
            for (int p = t - 64; p < LQ * NK; p += 192)
                ((float*)sPhi[ub ^ 1])[p] = 0.f;
        }
        // no barrier: next iteration's MFMA writes sM[ub^1] (unused by this C),
        // and its pre-C barrier orders sPhi[ub^1] zeroing vs C atomics.
    }
}

__global__ void knrm_combine(const float* __restrict__ logits, float* __restrict__ out)
{
    const int b = blockIdx.x * blockDim.x + threadIdx.x;
    if (b < NB) {
        out[b] = 1.0f / (1.0f + __expf(logits[NB + b] - logits[b]));
    }
}

// ============ Fallback (fp32 gathers, R5 path) if ws too small ==============
__device__ __forceinline__ short f2bf(float f, float& back) {
    unsigned u = __builtin_bit_cast(unsigned, f);
    unsigned r = (u + 0x7FFFu + ((u >> 16) & 1u)) >> 16;
    back = __builtin_bit_cast(float, r << 16);
    return (short)r;
}

__device__ __forceinline__ bf16x8 make_frag(float4 f0, float4 f1, float& sq) {
    bf16x8 v; float bk;
    v[0] = f2bf(f0.x, bk); sq += bk * bk;
    v[1] = f2bf(f0.y, bk); sq += bk * bk;
    v[2] = f2bf(f0.z, bk); sq += bk * bk;
    v[3] = f2bf(f0.w, bk); sq += bk * bk;
    v[4] = f2bf(f1.x, bk); sq += bk * bk;
    v[5] = f2bf(f1.y, bk); sq += bk * bk;
    v[6] = f2bf(f1.z, bk); sq += bk * bk;
    v[7] = f2bf(f1.w, bk); sq += bk * bk;
    return v;
}

__global__ __launch_bounds__(256, 4) void knrm_fused(
    const int* __restrict__ q1, const int* __restrict__ d1,
    const int* __restrict__ q2, const int* __restrict__ d2,
    const float* __restrict__ emb,
    const float* __restrict__ W1, const float* __restrict__ b1,
    const float* __restrict__ W2, const float* __restrict__ b2,
    const float* __restrict__ W3, const float* __restrict__ b3,
    float* __restrict__ logits)
{
    __shared__ float sM[LD][20];
    __shared__ float sPhi[LQ][NK];
    __shared__ float sX[NK];
    __shared__ float sH1[10];
    __shared__ float sH2[5];

    const int bp   = blockIdx.x;
    const int b    = bp & (NB - 1);
    const int pred = bp >> 10;
    const int t    = threadIdx.x;
    const int lane = t & 63, wave = t >> 6;
    const int c    = lane & 15, quad = lane >> 4;
    const int* __restrict__ qi = pred ? q2 : q1;
    const int* __restrict__ di = pred ? d2 : d1;
    const float4* emb4 = (const float4*)emb;

    for (int p = t; p < LQ * NK; p += 256) ((float*)sPhi)[p] = 0.f;

    bf16x8 aF[2][4];
    float  rqv[2][4];
    #pragma unroll
    for (int Mt = 0; Mt < 2; ++Mt) {
        const int row = Mt * 16 + c;
        const int id  = qi[b * LQ + (row < LQ ? row : LQ - 1)];
        const float4* qb = emb4 + (size_t)id * E4;
        float qs = 0.f;
        #pragma unroll
        for (int ks = 0; ks < 4; ++ks) {
            float4 f0 = qb[ks * 8 + quad * 2];
            float4 f1 = qb[ks * 8 + quad * 2 + 1];
            aF[Mt][ks] = make_frag(f0, f1, qs);
        }
        if (row >= LQ) {
            #pragma unroll
            for (int ks = 0; ks < 4; ++ks) aF[Mt][ks] = (bf16x8)0;
            qs = 0.f;
        }
        qs += __shfl_xor(qs, 16);
        qs += __shfl_xor(qs, 32);
        const float rq = rsqrtf(qs + 1e-6f);
        #pragma unroll
        for (int r = 0; r < 4; ++r)
            rqv[Mt][r] = __shfl(rq, quad * 4 + r);
    }

    for (int tile = wave; tile < 13; tile += 4) {
        const int j  = tile * 16 + c;
        const int id = di[b * LD + (j < LD ? j : LD - 1)];
        const float4* db = emb4 + (size_t)id * E4;
        bf16x8 bF[4];
        float dsq = 0.f;
        #pragma unroll
        for (int ks = 0; ks < 4; ++ks) {
            float4 f0 = db[ks * 8 + quad * 2];
            float4 f1 = db[ks * 8 + quad * 2 + 1];
            bF[ks] = make_frag(f0, f1, dsq);
        }
        dsq += __shfl_xor(dsq, 16);
        dsq += __shfl_xor(dsq, 32);
        const float rd = rsqrtf(dsq + 1e-6f);

        f32x4 acc0 = {0.f, 0.f, 0.f, 0.f};
        f32x4 acc1 = {0.f, 0.f, 0.f, 0.f};
        #pragma unroll
        for (int ks = 0; ks < 4; ++ks) {
            acc0 = __builtin_amdgcn_mfma_f32_16x16x32_bf16(aF[0][ks], bF[ks], acc0, 0, 0, 0);
            acc1 = __builtin_amdgcn_mfma_f32_16x16x32_bf16(aF[1][ks], bF[ks], acc1, 0, 0, 0);
        }
        if (j < LD) {
            float4 v0;
            v0.x = acc0[0] * rqv[0][0] * rd;
            v0.y = acc0[1] * rqv[0][1] * rd;
            v0.z = acc0[2] * rqv[0][2] * rd;
            v0.w = acc0[3] * rqv[0][3] * rd;
            *(float4*)&sM[j][quad * 4] = v0;
            if (quad == 0) {
                float4 v1;
                v1.x = acc1[0] * rqv[1][0] * rd;
                v1.y = acc1[1] * rqv[1][1] * rd;
                v1.z = acc1[2] * rqv[1][2] * rd;
                v1.w = acc1[3] * rqv[1][3] * rd;
                *(float4*)&sM[j][16] = v1;
            }
        }
    }
    __syncthreads();

    if (t < 240) {
        const int i = t / 12, slice = t % 12;
        const int j0 = slice * 17;
        const int j1 = (j0 + 17 < LD) ? (j0 + 17) : LD;
        const float C2  = -72.13475204f;
        const float B2  = 144.26950408f;
        const float C2E = -721347.5204f;

        float s00 = 0.f, s01 = 0.f, s02 = 0.f, s03 = 0.f, s04 = 0.f;
        float s05 = 0.f, s06 = 0.f, s07 = 0.f, s08 = 0.f, s09 = 0.f;
        float s10 = 0.f, s11 = 0.f, s12 = 0.f, s13 = 0.f, s14 = 0.f;
        float s15 = 0.f, s16 = 0.f, s17 = 0.f, s18 = 0.f, s19 = 0.f;
        float s20 = 0.f;

        for (int j = j0; j < j1; ++j) {
            const float m  = sM[j][i];
            const float a2 = C2 * (m * m);
            const float bb = B2 * m;
            #define KS(ACC, MU) \
                ACC += fast_exp2(fmaf((MU), bb, a2 + (-72.13475204f) * ((MU) * (MU))));
            KS(s00, -0.95f) KS(s01, -0.85f) KS(s02, -0.75f) KS(s03, -0.65f)
            KS(s04, -0.55f) KS(s05, -0.45f) KS(s06, -0.35f) KS(s07, -0.25f)
            KS(s08, -0.15f) KS(s09, -0.05f) KS(s10,  0.05f) KS(s11,  0.15f)
            KS(s12,  0.25f) KS(s13,  0.35f) KS(s14,  0.45f) KS(s15,  0.55f)
            KS(s16,  0.65f) KS(s17,  0.75f) KS(s18,  0.85f) KS(s19,  0.95f)
            #undef KS
            const float dd = m - 1.0f;
            s20 += fast_exp2(dd * dd * C2E);
        }
        atomicAdd(&sPhi[i][ 0], s00); atomicAdd(&sPhi[i][ 1], s01);
        atomicAdd(&sPhi[i][ 2], s02); atomicAdd(&sPhi[i][ 3], s03);
        atomicAdd(&sPhi[i][ 4], s04); atomicAdd(&sPhi[i][ 5], s05);
        atomicAdd(&sPhi[i][ 6], s06); atomicAdd(&sPhi[i][ 7], s07);
        atomicAdd(&sPhi[i][ 8], s08); atomicAdd(&sPhi[i][ 9], s09);
        atomicAdd(&sPhi[i][10], s10); atomicAdd(&sPhi[i][11], s11);
        atomicAdd(&sPhi[i][12], s12); atomicAdd(&sPhi[i][13], s13);
        atomicAdd(&sPhi[i][14], s14); atomicAdd(&sPhi[i][15], s15);
        atomicAdd(&sPhi[i][16], s16); atomicAdd(&sPhi[i][17], s17);
        atomicAdd(&sPhi[i][18], s18); atomicAdd(&sPhi[i][19], s19);
        atomicAdd(&sPhi[i][20], s20);
    }
    __syncthreads();

    if (t < NK) {
        float s = 0.f;
        #pragma unroll
        for (int i = 0; i < LQ; ++i) s += __logf(1.0f + sPhi[i][t]);
        sX[t] = s;
    }
    __syncthreads();

    if (t < 10) {
        float v = b1[t];
        #pragma unroll
        for (int k = 0; k < NK; ++k) v += W1[t * NK + k] * sX[k];
        sH1[t] = fmaxf(v, 0.f);
    }
    __syncthreads();

    if (t < 5) {
        float v = b2[t];
        #pragma unroll
        for (int k = 0; k < 10; ++k) v += W2[t * 10 + k] * sH1[k];
        sH2[t] = fmaxf(v, 0.f);
    }
    __syncthreads();

    if (t == 0) {
        float v = b3[0];
        #pragma unroll
        for (int k = 0; k < 5; ++k) v += W3[k] * sH2[k];
        logits[pred * NB + b] = v;
    }
}

extern "C" void kernel_launch(void* const* d_in, const int* in_sizes, int n_in,
                              void* d_out, int out_size, void* d_ws, size_t ws_size,
                              hipStream_t stream) {
    const int embN = in_sizes[4];                    // 100000*128
    const size_t TBYTES = (size_t)embN * 2;          // 25.6 MB bf16 table
    if (ws_size >= TBYTES + 2 * NB * sizeof(float)) {
        unsigned short* ebf = (unsigned short*)d_ws;
        float* logits = (float*)((char*)d_ws + TBYTES);
        knrm_cast<<<2048, 256, 0, stream>>>((const float*)d_in[4], ebf, embN / 4);
        knrm_pipe<<<GRID, 256, 0, stream>>>(
            (const int*)d_in[0], (const int*)d_in[1],
            (const int*)d_in[2], (const int*)d_in[3],
            ebf,
            (const float*)d_in[5], (const float*)d_in[6],
            (const float*)d_in[7], (const float*)d_in[8],
            (const float*)d_in[9], (const float*)d_in[10],
            logits);
        knrm_combine<<<(NB + 255) / 256, 256, 0, stream>>>(logits, (float*)d_out);
    } else {
        float* logits = (float*)d_ws;
        knrm_fused<<<2 * NB, 256, 0, stream>>>(
            (const int*)d_in[0], (const int*)d_in[1],
            (const int*)d_in[2], (const int*)d_in[3],
            (const float*)d_in[4],
            (const float*)d_in[5], (const float*)d_in[6],
            (const float*)d_in[7], (const float*)d_in[8],
            (const float*)d_in[9], (const float*)d_in[10],
            logits);
        knrm_combine<<<(NB + 255) / 256, 256, 0, stream>>>(logits, (float*)d_out);
    }
}

// Round 8
// 208.496 us; speedup vs baseline: 1.0962x; 1.0962x over previous
//
#include <hip/hip_runtime.h>

#define NB 1024
#define LQ 20
#define LD 200
#define E4 32      // 128 floats / 4
#define NK 21

typedef __attribute__((ext_vector_type(8))) short bf16x8;   // 8 bf16 = 4 VGPRs
typedef __attribute__((ext_vector_type(4))) float f32x4;

__device__ __forceinline__ short f2bf(float f, float& back) {
    unsigned u = __builtin_bit_cast(unsigned, f);
    unsigned r = (u + 0x7FFFu + ((u >> 16) & 1u)) >> 16;   // RNE
    back = __builtin_bit_cast(float, r << 16);
    return (short)r;
}

__device__ __forceinline__ bf16x8 make_frag(float4 f0, float4 f1, float& sq) {
    bf16x8 v; float bk;
    v[0] = f2bf(f0.x, bk); sq += bk * bk;
    v[1] = f2bf(f0.y, bk); sq += bk * bk;
    v[2] = f2bf(f0.z, bk); sq += bk * bk;
    v[3] = f2bf(f0.w, bk); sq += bk * bk;
    v[4] = f2bf(f1.x, bk); sq += bk * bk;
    v[5] = f2bf(f1.y, bk); sq += bk * bk;
    v[6] = f2bf(f1.z, bk); sq += bk * bk;
    v[7] = f2bf(f1.w, bk); sq += bk * bk;
    return v;
}

__device__ __forceinline__ float fast_exp2(float x) {
#if __has_builtin(__builtin_amdgcn_exp2f)
    return __builtin_amdgcn_exp2f(x);
#else
    return __expf(x * 0.69314718056f);
#endif
}

// One block per (batch, pred). fp32 gathers (no ws table -> no poison tax).
__global__ __launch_bounds__(256, 4) void knrm_fused(
    const int* __restrict__ q1, const int* __restrict__ d1,
    const int* __restrict__ q2, const int* __restrict__ d2,
    const float* __restrict__ emb,
    const float* __restrict__ W1, const float* __restrict__ b1,
    const float* __restrict__ W2, const float* __restrict__ b2,
    const float* __restrict__ W3, const float* __restrict__ b3,
    float* __restrict__ logits)
{
    __shared__ float sM[LD][20];     // 16 KB, [j][i]
    __shared__ float sPhi[LQ][NK];
    __shared__ float sX[NK];
    __shared__ float sH1[10];
    __shared__ float sH2[5];

    const int bp   = blockIdx.x;
    const int b    = bp & (NB - 1);
    const int pred = bp >> 10;
    const int t    = threadIdx.x;
    const int lane = t & 63, wave = t >> 6;
    const int c    = lane & 15, quad = lane >> 4;
    const int* __restrict__ qi = pred ? q2 : q1;
    const int* __restrict__ di = pred ? d2 : d1;
    const float4* emb4 = (const float4*)emb;

    for (int p = t; p < LQ * NK; p += 256) ((float*)sPhi)[p] = 0.f;

    // ---- A (Q) fragments: 2 M-tiles x 4 K-steps; norms from bf16 values ----
    bf16x8 aF[2][4];
    float  rqv[2][4];
    #pragma unroll
    for (int Mt = 0; Mt < 2; ++Mt) {
        const int row = Mt * 16 + c;
        const int id  = qi[b * LQ + (row < LQ ? row : LQ - 1)];
        const float4* qb = emb4 + (size_t)id * E4;
        float qs = 0.f;
        #pragma unroll
        for (int ks = 0; ks < 4; ++ks) {
            float4 f0 = qb[ks * 8 + quad * 2];
            float4 f1 = qb[ks * 8 + quad * 2 + 1];
            aF[Mt][ks] = make_frag(f0, f1, qs);
        }
        if (row >= LQ) {
            #pragma unroll
            for (int ks = 0; ks < 4; ++ks) aF[Mt][ks] = (bf16x8)0;
            qs = 0.f;
        }
        qs += __shfl_xor(qs, 16);
        qs += __shfl_xor(qs, 32);
        const float rq = rsqrtf(qs + 1e-6f);
        #pragma unroll
        for (int r = 0; r < 4; ++r)
            rqv[Mt][r] = __shfl(rq, quad * 4 + r);
    }

    // ---- Phase B: MFMA over 13 N-tiles of 16 d-cols ----
    for (int tile = wave; tile < 13; tile += 4) {
        const int j  = tile * 16 + c;
        const int id = di[b * LD + (j < LD ? j : LD - 1)];
        const float4* db = emb4 + (size_t)id * E4;
        bf16x8 bF[4];
        float dsq = 0.f;
        #pragma unroll
        for (int ks = 0; ks < 4; ++ks) {
            float4 f0 = db[ks * 8 + quad * 2];
            float4 f1 = db[ks * 8 + quad * 2 + 1];
            bF[ks] = make_frag(f0, f1, dsq);
        }
        dsq += __shfl_xor(dsq, 16);
        dsq += __shfl_xor(dsq, 32);
        const float rd = rsqrtf(dsq + 1e-6f);

        f32x4 acc0 = {0.f, 0.f, 0.f, 0.f};
        f32x4 acc1 = {0.f, 0.f, 0.f, 0.f};
        #pragma unroll
        for (int ks = 0; ks < 4; ++ks) {
            acc0 = __builtin_amdgcn_mfma_f32_16x16x32_bf16(aF[0][ks], bF[ks], acc0, 0, 0, 0);
            acc1 = __builtin_amdgcn_mfma_f32_16x16x32_bf16(aF[1][ks], bF[ks], acc1, 0, 0, 0);
        }
        if (j < LD) {
            // C layout: col = lane&15 (=j), row = quad*4 + reg
            float4 v0;
            v0.x = acc0[0] * rqv[0][0] * rd;
            v0.y = acc0[1] * rqv[0][1] * rd;
            v0.z = acc0[2] * rqv[0][2] * rd;
            v0.w = acc0[3] * rqv[0][3] * rd;
            *(float4*)&sM[j][quad * 4] = v0;
            if (quad == 0) {
                float4 v1;
                v1.x = acc1[0] * rqv[1][0] * rd;
                v1.y = acc1[1] * rqv[1][1] * rd;
                v1.z = acc1[2] * rqv[1][2] * rd;
                v1.w = acc1[3] * rqv[1][3] * rd;
                *(float4*)&sM[j][16] = v1;
            }
        }
    }
    __syncthreads();

    // ---- Phase C: RBF kernels via geometric-ladder recurrence ----
    // term_k = 2^(C2(m-mu_k)^2). Adjacent ratios: r_{k+1} = r_k * RHO,
    // RHO = 2^(0.02*C2) = e^-1. Per 5-kernel block: 2 exps + 7 mul + 5 add.
    // Underflow-safe: anchor flush (arg<-126) implies every block term <= 2^-61.
    if (t < 240) {
        const int i = t / 12, slice = t % 12;
        const int j0 = slice * 17;
        const int j1 = (j0 + 17 < LD) ? (j0 + 17) : LD;
        const float C2  = -72.13475204f;     // -50*log2(e)
        const float C2E = -721347.5204f;     // -5e5*log2(e)
        const float RHO = 0.36787944117f;    // exp(-1)

        float s00 = 0.f, s01 = 0.f, s02 = 0.f, s03 = 0.f, s04 = 0.f;
        float s05 = 0.f, s06 = 0.f, s07 = 0.f, s08 = 0.f, s09 = 0.f;
        float s10 = 0.f, s11 = 0.f, s12 = 0.f, s13 = 0.f, s14 = 0.f;
        float s15 = 0.f, s16 = 0.f, s17 = 0.f, s18 = 0.f, s19 = 0.f;
        float s20 = 0.f;

        for (int j = j0; j < j1; ++j) {
            const float m    = sM[j][i];
            const float a2   = C2 * (m * m);
            const float bb   = 144.26950409f * m;    // -2*C2*m
            const float bb01 = 14.426950409f * m;    // 0.1*bb

            // anchor t = 2^(C2(m-MUa)^2); ratio r = 2^(0.1*bb + C2*(0.02a-0.18))
            #define KBLOCK(SA0, SA1, SA2, SA3, SA4, MUa, RA) { \
                float t_ = fast_exp2(fmaf((MUa), bb, a2 + (-72.13475204f) * ((MUa) * (MUa)))); \
                float r_ = fast_exp2(bb01 + (RA)); \
                SA0 += t_; \
                t_ *= r_;            SA1 += t_; \
                r_ *= RHO; t_ *= r_; SA2 += t_; \
                r_ *= RHO; t_ *= r_; SA3 += t_; \
                r_ *= RHO; t_ *= r_; SA4 += t_; }

            KBLOCK(s00, s01, s02, s03, s04, -0.95f, 12.98425537f)   // k=0..4,  a=0
            KBLOCK(s05, s06, s07, s08, s09, -0.45f, 5.770780163f)   // k=5..9,  a=5
            KBLOCK(s10, s11, s12, s13, s14,  0.05f, -1.442695041f)  // k=10..14, a=10
            KBLOCK(s15, s16, s17, s18, s19,  0.55f, -8.656170245f)  // k=15..19, a=15
            #undef KBLOCK

            // exact kernel (sigma=0.001): zero unless m > 0.985 -> wave-skip
            if (__any(m > 0.985f)) {
                const float dd = m - 1.0f;
                s20 += fast_exp2(dd * dd * C2E);
            }
        }
        atomicAdd(&sPhi[i][ 0], s00); atomicAdd(&sPhi[i][ 1], s01);
        atomicAdd(&sPhi[i][ 2], s02); atomicAdd(&sPhi[i][ 3], s03);
        atomicAdd(&sPhi[i][ 4], s04); atomicAdd(&sPhi[i][ 5], s05);
        atomicAdd(&sPhi[i][ 6], s06); atomicAdd(&sPhi[i][ 7], s07);
        atomicAdd(&sPhi[i][ 8], s08); atomicAdd(&sPhi[i][ 9], s09);
        atomicAdd(&sPhi[i][10], s10); atomicAdd(&sPhi[i][11], s11);
        atomicAdd(&sPhi[i][12], s12); atomicAdd(&sPhi[i][13], s13);
        atomicAdd(&sPhi[i][14], s14); atomicAdd(&sPhi[i][15], s15);
        atomicAdd(&sPhi[i][16], s16); atomicAdd(&sPhi[i][17], s17);
        atomicAdd(&sPhi[i][18], s18); atomicAdd(&sPhi[i][19], s19);
        atomicAdd(&sPhi[i][20], s20);
    }
    __syncthreads();

    // ---- log1p + sum over i ----
    if (t < NK) {
        float s = 0.f;
        #pragma unroll
        for (int i = 0; i < LQ; ++i) s += __logf(1.0f + sPhi[i][t]);
        sX[t] = s;   // s >= 0, relu no-op
    }
    __syncthreads();

    if (t < 10) {
        float v = b1[t];
        #pragma unroll
        for (int k = 0; k < NK; ++k) v += W1[t * NK + k] * sX[k];
        sH1[t] = fmaxf(v, 0.f);
    }
    __syncthreads();

    if (t < 5) {
        float v = b2[t];
        #pragma unroll
        for (int k = 0; k < 10; ++k) v += W2[t * 10 + k] * sH1[k];
        sH2[t] = fmaxf(v, 0.f);
    }
    __syncthreads();

    if (t == 0) {
        float v = b3[0];
        #pragma unroll
        for (int k = 0; k < 5; ++k) v += W3[k] * sH2[k];
        logits[pred * NB + b] = v;
    }
}

__global__ void knrm_combine(const float* __restrict__ logits, float* __restrict__ out)
{
    const int b = blockIdx.x * blockDim.x + threadIdx.x;
    if (b < NB) {
        out[b] = 1.0f / (1.0f + __expf(logits[NB + b] - logits[b]));
    }
}

extern "C" void kernel_launch(void* const* d_in, const int* in_sizes, int n_in,
                              void* d_out, int out_size, void* d_ws, size_t ws_size,
                              hipStream_t stream) {
    float* logits = (float*)d_ws;   // 2*NB floats
    knrm_fused<<<2 * NB, 256, 0, stream>>>(
        (const int*)d_in[0], (const int*)d_in[1],
        (const int*)d_in[2], (const int*)d_in[3],
        (const float*)d_in[4],
        (const float*)d_in[5], (const float*)d_in[6],
        (const float*)d_in[7], (const float*)d_in[8],
        (const float*)d_in[9], (const float*)d_in[10],
        logits);
    knrm_combine<<<(NB + 255) / 256, 256, 0, stream>>>(logits, (float*)d_out);
}